// Round 4
// baseline (890.239 us; speedup 1.0000x reference)
//
#include <hip/hip_runtime.h>
#include <math.h>

typedef float f32x4 __attribute__((ext_vector_type(4)));
typedef __bf16 bh8 __attribute__((ext_vector_type(8)));

constexpr int Bc = 32;
constexpr int Tc = 4096;
constexpr int Dc = 256;
constexpr int Hc = 128;
constexpr float kTempInv = 2.0f;
constexpr float kThr = 0.4f;
constexpr float kLnEps = 1e-5f;
constexpr float kNormEps = 1e-12f;
constexpr float kInvSqrt2 = 0.70710678118654752440f;

__device__ __forceinline__ unsigned short f2bf(float f) {
  unsigned u = __float_as_uint(f);
  u += 0x7FFFu + ((u >> 16) & 1u);
  return (unsigned short)(u >> 16);
}
__device__ __forceinline__ float bf2f(unsigned short s) {
  return __uint_as_float(((unsigned)s) << 16);
}

// ---------------- K1: attention scores ----------------
__global__ __launch_bounds__(256) void k_scores(const float* __restrict__ x,
                                                const float* __restrict__ tq,
                                                float* __restrict__ scores) {
  const int wave = threadIdx.x >> 6;
  const int lane = threadIdx.x & 63;
  const int base = blockIdx.x * 32 + wave * 8;
  const float4 q4 = reinterpret_cast<const float4*>(tq)[lane];
  for (int i = 0; i < 8; ++i) {
    const int tok = base + i;
    const float4 xv = reinterpret_cast<const float4*>(x + (size_t)tok * Dc)[lane];
    float p = xv.x * q4.x + xv.y * q4.y + xv.z * q4.z + xv.w * q4.w;
    #pragma unroll
    for (int off = 32; off > 0; off >>= 1) p += __shfl_xor(p, off, 64);
    if (lane == 0) scores[tok] = p * kTempInv;
  }
}

// ---------------- K2: per-batch softmax stats ----------------
__global__ __launch_bounds__(1024) void k_smstats(const float* __restrict__ scores,
                                                  float2* __restrict__ stats) {
  const int b = blockIdx.x, tid = threadIdx.x;
  const float4 v = reinterpret_cast<const float4*>(scores + (size_t)b * Tc)[tid];
  __shared__ float red[16];
  float m = fmaxf(fmaxf(v.x, v.y), fmaxf(v.z, v.w));
  #pragma unroll
  for (int off = 32; off > 0; off >>= 1) m = fmaxf(m, __shfl_xor(m, off, 64));
  if ((tid & 63) == 0) red[tid >> 6] = m;
  __syncthreads();
  if (tid == 0) {
    float gm = red[0];
    for (int i = 1; i < 16; ++i) gm = fmaxf(gm, red[i]);
    red[0] = gm;
  }
  __syncthreads();
  const float gmax = red[0];
  float s = expf(v.x - gmax) + expf(v.y - gmax) + expf(v.z - gmax) + expf(v.w - gmax);
  #pragma unroll
  for (int off = 32; off > 0; off >>= 1) s += __shfl_xor(s, off, 64);
  __syncthreads();
  if ((tid & 63) == 0) red[tid >> 6] = s;
  __syncthreads();
  if (tid == 0) {
    float t = 0.0f;
    for (int i = 0; i < 16; ++i) t += red[i];
    stats[b] = make_float2(gmax, t);
  }
}

// ---------------- K3: weighted sum -> main_topic ----------------
__global__ __launch_bounds__(256) void k_wsum(const float* __restrict__ x,
                                              const float* __restrict__ scores,
                                              const float2* __restrict__ stats,
                                              float* __restrict__ mt) {
  const int b = blockIdx.x >> 4;
  const int chunk = blockIdx.x & 15;
  const int d = threadIdx.x;
  const float2 st = stats[b];
  const int t0 = chunk * 256;
  const float* xb = x + ((size_t)b * Tc + t0) * Dc + d;
  const float* sb = scores + (size_t)b * Tc + t0;
  float acc = 0.0f;
  for (int i = 0; i < 256; ++i) {
    const float w = expf(sb[i] - st.x);
    acc += w * xb[(size_t)i * Dc];
  }
  atomicAdd(&mt[b * Dc + d], acc * (1.0f / st.y));
}

// ---------------- K4: encode main_topic (exact fp32) ----------------
__global__ __launch_bounds__(256) void k_tenc(
    const float* __restrict__ mt, const float* __restrict__ W1,
    const float* __restrict__ b1, const float* __restrict__ lng,
    const float* __restrict__ lnb, const float* __restrict__ W2,
    const float* __restrict__ b2, float* __restrict__ tnorm) {
  const int b = blockIdx.x, j = threadIdx.x;
  __shared__ float v[Dc];
  __shared__ float g[Dc];
  __shared__ float red[4];
  v[j] = mt[b * Dc + j];
  __syncthreads();
  float h = b1[j];
  for (int k = 0; k < Dc; ++k) h += v[k] * W1[(size_t)k * Dc + j];
  float s = h;
  #pragma unroll
  for (int off = 32; off > 0; off >>= 1) s += __shfl_xor(s, off, 64);
  if ((j & 63) == 0) red[j >> 6] = s;
  __syncthreads();
  const float mu = (red[0] + red[1] + red[2] + red[3]) * (1.0f / Dc);
  __syncthreads();
  const float dev = h - mu;
  float q = dev * dev;
  #pragma unroll
  for (int off = 32; off > 0; off >>= 1) q += __shfl_xor(q, off, 64);
  if ((j & 63) == 0) red[j >> 6] = q;
  __syncthreads();
  const float var = (red[0] + red[1] + red[2] + red[3]) * (1.0f / Dc);
  float hn = dev / sqrtf(var + kLnEps) * lng[j] + lnb[j];
  hn = 0.5f * hn * (1.0f + erff(hn * kInvSqrt2));
  g[j] = hn;
  __syncthreads();
  float z = 0.0f;
  if (j < Hc) {
    z = b2[j];
    for (int k = 0; k < Dc; ++k) z += g[k] * W2[(size_t)k * Hc + j];
  }
  float q2 = z * z;
  #pragma unroll
  for (int off = 32; off > 0; off >>= 1) q2 += __shfl_xor(q2, off, 64);
  __syncthreads();
  if ((j & 63) == 0) red[j >> 6] = q2;
  __syncthreads();
  if (j < Hc) {
    const float nrm = sqrtf(red[0] + red[1] + red[2] + red[3]);
    tnorm[b * Hc + j] = z / fmaxf(nrm, kNormEps);
  }
}

// ---------------- K-prep: W1^T, W2^T split into bf16 hi/lo ----------------
__global__ __launch_bounds__(256) void k_prep(const float* __restrict__ W1,
                                              const float* __restrict__ W2,
                                              unsigned short* __restrict__ w1h,
                                              unsigned short* __restrict__ w1l,
                                              unsigned short* __restrict__ w2h,
                                              unsigned short* __restrict__ w2l) {
  const int g = blockIdx.x * 256 + threadIdx.x;
  if (blockIdx.x < 64) {  // W1 [256 x 256] -> W1T[n][k]
    const int n = g >> 6;
    const int kq = (g & 63) * 4;
    unsigned h[2] = {0, 0}, l[2] = {0, 0};
    #pragma unroll
    for (int j = 0; j < 4; ++j) {
      const float v = W1[(size_t)(kq + j) * Dc + n];
      const unsigned short hb = f2bf(v);
      const unsigned short lb = f2bf(v - bf2f(hb));
      h[j >> 1] |= ((unsigned)hb) << ((j & 1) * 16);
      l[j >> 1] |= ((unsigned)lb) << ((j & 1) * 16);
    }
    *reinterpret_cast<uint2*>(&w1h[(size_t)n * Dc + kq]) = make_uint2(h[0], h[1]);
    *reinterpret_cast<uint2*>(&w1l[(size_t)n * Dc + kq]) = make_uint2(l[0], l[1]);
  } else {  // W2 [256 x 128] -> W2T[h][k]
    const int g2 = g - 16384;
    const int n = g2 >> 6;
    const int kq = (g2 & 63) * 4;
    unsigned h[2] = {0, 0}, l[2] = {0, 0};
    #pragma unroll
    for (int j = 0; j < 4; ++j) {
      const float v = W2[(size_t)(kq + j) * Hc + n];
      const unsigned short hb = f2bf(v);
      const unsigned short lb = f2bf(v - bf2f(hb));
      h[j >> 1] |= ((unsigned)hb) << ((j & 1) * 16);
      l[j >> 1] |= ((unsigned)lb) << ((j & 1) * 16);
    }
    *reinterpret_cast<uint2*>(&w2h[(size_t)n * Dc + kq]) = make_uint2(h[0], h[1]);
    *reinterpret_cast<uint2*>(&w2l[(size_t)n * Dc + kq]) = make_uint2(l[0], l[1]);
  }
}

// ---------------- K5: MFMA encode + relevance mask (K-split LDS, 4 blk/CU) ----
// 64 tokens/block, 4 waves (2M x 2N). Staging & h-transpose buffers hold HALF
// the K range (128 cols) -> peak LDS ~40KB -> 4 blocks/CU.
__global__ __launch_bounds__(256, 4) void k_encode_mfma(
    const float* __restrict__ x,
    const unsigned short* __restrict__ w1h, const unsigned short* __restrict__ w1l,
    const unsigned short* __restrict__ w2h, const unsigned short* __restrict__ w2l,
    const float* __restrict__ b1, const float* __restrict__ lng,
    const float* __restrict__ lnb, const float* __restrict__ b2,
    const float* __restrict__ tnorm, unsigned char* __restrict__ irr) {
  constexpr int LH = 136;  // bf16 elems per 128-col row (+8 pad)
  __shared__ __align__(16) unsigned short s_hi[64 * LH];  // 17408 B
  __shared__ __align__(16) unsigned short s_lo[64 * LH];  // 17408 B
  __shared__ float ps[2][64];
  __shared__ float psD[2][64];
  __shared__ float p_b1[Dc], p_g[Dc], p_bb[Dc], p_b2[Hc], p_tn[Hc];

  const int tid = threadIdx.x;
  const size_t tok0 = (size_t)blockIdx.x * 64;
  const int b = (int)(tok0 >> 12);
  const int lane = tid & 63;
  const int wave = tid >> 6;
  const int wm = wave >> 1, wn = wave & 1;
  const int lrow = lane & 15, lkh = lane >> 4;

  p_b1[tid] = b1[tid];
  p_g[tid] = lng[tid];
  p_bb[tid] = lnb[tid];
  if (tid < Hc) {
    p_b2[tid] = b2[tid];
    p_tn[tid] = tnorm[b * Hc + tid];
  }

  f32x4 acc1[2][8];
  #pragma unroll
  for (int mt = 0; mt < 2; ++mt)
    #pragma unroll
    for (int nt = 0; nt < 8; ++nt) acc1[mt][nt] = (f32x4){0.f, 0.f, 0.f, 0.f};

  // ---- stage half of x (64 rows x 128 cols) as bf16 hi/lo ----
  auto stage_half = [&](int kh) {
    #pragma unroll
    for (int i = 0; i < 8; ++i) {
      const int f = tid + (i << 8);
      const int row = f >> 5, c4 = f & 31;
      const float4 v = *reinterpret_cast<const float4*>(
          x + (tok0 + row) * Dc + kh * 128 + c4 * 4);
      unsigned hp[2] = {0, 0}, lp[2] = {0, 0};
      const float vv[4] = {v.x, v.y, v.z, v.w};
      #pragma unroll
      for (int j = 0; j < 4; ++j) {
        const unsigned short hb = f2bf(vv[j]);
        const unsigned short lb = f2bf(vv[j] - bf2f(hb));
        hp[j >> 1] |= ((unsigned)hb) << ((j & 1) * 16);
        lp[j >> 1] |= ((unsigned)lb) << ((j & 1) * 16);
      }
      *reinterpret_cast<uint2*>(&s_hi[row * LH + c4 * 4]) = make_uint2(hp[0], hp[1]);
      *reinterpret_cast<uint2*>(&s_lo[row * LH + c4 * 4]) = make_uint2(lp[0], lp[1]);
    }
  };

  auto gemm1_half = [&](int kh) {
    for (int ks = 0; ks < 4; ++ks) {
      bh8 ah[2], al[2];
      #pragma unroll
      for (int mt = 0; mt < 2; ++mt) {
        const int off = (wm * 32 + mt * 16 + lrow) * LH + ks * 32 + lkh * 8;
        ah[mt] = *reinterpret_cast<const bh8*>(&s_hi[off]);
        al[mt] = *reinterpret_cast<const bh8*>(&s_lo[off]);
      }
      #pragma unroll
      for (int nt = 0; nt < 8; ++nt) {
        const size_t boff = (size_t)(wn * 128 + nt * 16 + lrow) * Dc +
                            kh * 128 + ks * 32 + lkh * 8;
        const bh8 bh = *reinterpret_cast<const bh8*>(&w1h[boff]);
        const bh8 bl = *reinterpret_cast<const bh8*>(&w1l[boff]);
        #pragma unroll
        for (int mt = 0; mt < 2; ++mt) {
          acc1[mt][nt] = __builtin_amdgcn_mfma_f32_16x16x32_bf16(ah[mt], bh, acc1[mt][nt], 0, 0, 0);
          acc1[mt][nt] = __builtin_amdgcn_mfma_f32_16x16x32_bf16(al[mt], bh, acc1[mt][nt], 0, 0, 0);
          acc1[mt][nt] = __builtin_amdgcn_mfma_f32_16x16x32_bf16(ah[mt], bl, acc1[mt][nt], 0, 0, 0);
        }
      }
    }
  };

  stage_half(0);
  __syncthreads();
  gemm1_half(0);
  __syncthreads();
  stage_half(1);
  __syncthreads();
  gemm1_half(1);

  // ---- bias + LN row stats (cross-wave via LDS partials) ----
  float s[2][4];
  #pragma unroll
  for (int mt = 0; mt < 2; ++mt)
    #pragma unroll
    for (int j = 0; j < 4; ++j) s[mt][j] = 0.0f;
  #pragma unroll
  for (int nt = 0; nt < 8; ++nt) {
    const int col = wn * 128 + nt * 16 + lrow;
    const float bv = p_b1[col];
    #pragma unroll
    for (int mt = 0; mt < 2; ++mt) {
      #pragma unroll
      for (int j = 0; j < 4; ++j) {
        acc1[mt][nt][j] += bv;
        s[mt][j] += acc1[mt][nt][j];
      }
    }
  }
  #pragma unroll
  for (int mt = 0; mt < 2; ++mt)
    #pragma unroll
    for (int j = 0; j < 4; ++j) {
      #pragma unroll
      for (int off = 8; off > 0; off >>= 1) s[mt][j] += __shfl_xor(s[mt][j], off, 64);
    }
  if (lrow == 0) {
    #pragma unroll
    for (int mt = 0; mt < 2; ++mt)
      #pragma unroll
      for (int j = 0; j < 4; ++j)
        ps[wn][wm * 32 + mt * 16 + lkh * 4 + j] = s[mt][j];
  }
  __syncthreads();  // also: all waves done reading staging buffers
  float mu[2][4];
  #pragma unroll
  for (int mt = 0; mt < 2; ++mt)
    #pragma unroll
    for (int j = 0; j < 4; ++j) {
      const int r = wm * 32 + mt * 16 + lkh * 4 + j;
      mu[mt][j] = (ps[0][r] + ps[1][r]) * (1.0f / Dc);
    }
  float q[2][4];
  #pragma unroll
  for (int mt = 0; mt < 2; ++mt)
    #pragma unroll
    for (int j = 0; j < 4; ++j) q[mt][j] = 0.0f;
  #pragma unroll
  for (int nt = 0; nt < 8; ++nt)
    #pragma unroll
    for (int mt = 0; mt < 2; ++mt)
      #pragma unroll
      for (int j = 0; j < 4; ++j) {
        const float d = acc1[mt][nt][j] - mu[mt][j];
        q[mt][j] += d * d;
      }
  #pragma unroll
  for (int mt = 0; mt < 2; ++mt)
    #pragma unroll
    for (int j = 0; j < 4; ++j) {
      #pragma unroll
      for (int off = 8; off > 0; off >>= 1) q[mt][j] += __shfl_xor(q[mt][j], off, 64);
    }
  if (lrow == 0) {
    #pragma unroll
    for (int mt = 0; mt < 2; ++mt)
      #pragma unroll
      for (int j = 0; j < 4; ++j)
        psD[wn][wm * 32 + mt * 16 + lkh * 4 + j] = q[mt][j];
  }
  __syncthreads();
  // ---- normalize + GELU, kept in registers (acc1 becomes h) ----
  #pragma unroll
  for (int mt = 0; mt < 2; ++mt)
    #pragma unroll
    for (int j = 0; j < 4; ++j) {
      const int r = wm * 32 + mt * 16 + lkh * 4 + j;
      const float var = (psD[0][r] + psD[1][r]) * (1.0f / Dc);
      const float inv = 1.0f / sqrtf(var + kLnEps);
      #pragma unroll
      for (int nt = 0; nt < 8; ++nt) {
        const int col = wn * 128 + nt * 16 + lrow;
        float hv = (acc1[mt][nt][j] - mu[mt][j]) * inv * p_g[col] + p_bb[col];
        hv = 0.5f * hv * (1.0f + erff(hv * kInvSqrt2));
        acc1[mt][nt][j] = hv;
      }
    }

  // ---- GEMM2 with K-split h-transpose through the (reused) staging buffer ----
  f32x4 acc2[2][4];
  #pragma unroll
  for (int mt = 0; mt < 2; ++mt)
    #pragma unroll
    for (int nt = 0; nt < 4; ++nt) acc2[mt][nt] = (f32x4){0.f, 0.f, 0.f, 0.f};

  auto hwrite = [&](int half) {
    if (wn == half) {
      #pragma unroll
      for (int nt = 0; nt < 8; ++nt) {
        const int colg = nt * 16 + lrow;  // local col in [0,128)
        #pragma unroll
        for (int mt = 0; mt < 2; ++mt)
          #pragma unroll
          for (int j = 0; j < 4; ++j) {
            const int row = wm * 32 + mt * 16 + lkh * 4 + j;
            const float hv = acc1[mt][nt][j];
            const unsigned short hb = f2bf(hv);
            s_hi[row * LH + colg] = hb;
            s_lo[row * LH + colg] = f2bf(hv - bf2f(hb));
          }
      }
    }
  };
  auto gemm2_half = [&](int kh) {
    for (int ks = 0; ks < 4; ++ks) {
      bh8 ah[2], al[2];
      #pragma unroll
      for (int mt = 0; mt < 2; ++mt) {
        const int off = (wm * 32 + mt * 16 + lrow) * LH + ks * 32 + lkh * 8;
        ah[mt] = *reinterpret_cast<const bh8*>(&s_hi[off]);
        al[mt] = *reinterpret_cast<const bh8*>(&s_lo[off]);
      }
      #pragma unroll
      for (int nt = 0; nt < 4; ++nt) {
        const size_t boff = (size_t)(wn * 64 + nt * 16 + lrow) * Dc +
                            kh * 128 + ks * 32 + lkh * 8;
        const bh8 bh = *reinterpret_cast<const bh8*>(&w2h[boff]);
        const bh8 bl = *reinterpret_cast<const bh8*>(&w2l[boff]);
        #pragma unroll
        for (int mt = 0; mt < 2; ++mt) {
          acc2[mt][nt] = __builtin_amdgcn_mfma_f32_16x16x32_bf16(ah[mt], bh, acc2[mt][nt], 0, 0, 0);
          acc2[mt][nt] = __builtin_amdgcn_mfma_f32_16x16x32_bf16(al[mt], bh, acc2[mt][nt], 0, 0, 0);
          acc2[mt][nt] = __builtin_amdgcn_mfma_f32_16x16x32_bf16(ah[mt], bl, acc2[mt][nt], 0, 0, 0);
        }
      }
    }
  };

  hwrite(0);
  __syncthreads();
  gemm2_half(0);
  __syncthreads();
  hwrite(1);
  __syncthreads();
  gemm2_half(1);

  // ---- cosine vs t_enc -> irr ----
  float ss[2][4], sd[2][4];
  #pragma unroll
  for (int mt = 0; mt < 2; ++mt)
    #pragma unroll
    for (int j = 0; j < 4; ++j) { ss[mt][j] = 0.0f; sd[mt][j] = 0.0f; }
  #pragma unroll
  for (int nt = 0; nt < 4; ++nt) {
    const int col2 = wn * 64 + nt * 16 + lrow;
    const float b2v = p_b2[col2], tv = p_tn[col2];
    #pragma unroll
    for (int mt = 0; mt < 2; ++mt)
      #pragma unroll
      for (int j = 0; j < 4; ++j) {
        const float z = acc2[mt][nt][j] + b2v;
        ss[mt][j] += z * z;
        sd[mt][j] += z * tv;
      }
  }
  #pragma unroll
  for (int mt = 0; mt < 2; ++mt)
    #pragma unroll
    for (int j = 0; j < 4; ++j) {
      #pragma unroll
      for (int off = 8; off > 0; off >>= 1) {
        ss[mt][j] += __shfl_xor(ss[mt][j], off, 64);
        sd[mt][j] += __shfl_xor(sd[mt][j], off, 64);
      }
    }
  if (lrow == 0) {
    #pragma unroll
    for (int mt = 0; mt < 2; ++mt)
      #pragma unroll
      for (int j = 0; j < 4; ++j) {
        const int r = wm * 32 + mt * 16 + lkh * 4 + j;
        ps[wn][r] = ss[mt][j];
        psD[wn][r] = sd[mt][j];
      }
  }
  __syncthreads();
  if (tid < 64) {
    const float S = ps[0][tid] + ps[1][tid];
    const float Dd = psD[0][tid] + psD[1][tid];
    const float rel = Dd / fmaxf(sqrtf(S), kNormEps);
    irr[tok0 + tid] = (rel < kThr) ? (unsigned char)1 : (unsigned char)0;
  }
}

// ---------------- K6: radix-4 Stockham FFT, 4 channels/block, direct ----------
__device__ __forceinline__ float2 cmul(const float2 w, const float2 v) {
  return make_float2(w.x * v.x - w.y * v.y, w.x * v.y + w.y * v.x);
}

// 6 radix-4 stages over 4096 points; sgn=+1 forward (tw = e^{-2pi i k/4096}),
// sgn=-1 inverse (conjugate twiddles, j -> -j). Ends back in A buffers.
__device__ void fft4_run(float2* A0, float2* B0, float2* A1, float2* B1,
                         const float2* __restrict__ tw, const int tid,
                         const float sgn) {
  float2 *s0 = A0, *d0 = B0, *s1 = A1, *d1 = B1;
  int sdiv = 1;
  for (int st = 0; st < 6; ++st) {
    const int qq = tid & (sdiv - 1);
    const int ti = tid - qq;            // = p * sdiv, in [0,1024)
    float2 w1 = tw[ti];
    w1.y *= sgn;
    const float2 w2 = cmul(w1, w1);
    const float2 w3 = cmul(w2, w1);
    const int wb = (ti << 2) + qq;
    #pragma unroll
    for (int sq = 0; sq < 2; ++sq) {
      const float2* S = sq ? s1 : s0;
      float2* D = sq ? d1 : d0;
      const float2 a = S[tid];
      const float2 b = S[tid + 1024];
      const float2 c = S[tid + 2048];
      const float2 d = S[tid + 3072];
      const float apcx = a.x + c.x, apcy = a.y + c.y;
      const float amcx = a.x - c.x, amcy = a.y - c.y;
      const float bpdx = b.x + d.x, bpdy = b.y + d.y;
      const float bmdx = (b.x - d.x) * sgn, bmdy = (b.y - d.y) * sgn;
      D[wb] = make_float2(apcx + bpdx, apcy + bpdy);
      D[wb + sdiv] = cmul(w1, make_float2(amcx + bmdy, amcy - bmdx));
      D[wb + 2 * sdiv] = cmul(w2, make_float2(apcx - bpdx, apcy - bpdy));
      D[wb + 3 * sdiv] = cmul(w3, make_float2(amcx - bmdy, amcy + bmdx));
    }
    __syncthreads();
    float2* t = s0; s0 = d0; d0 = t;
    t = s1; s1 = d1; d1 = t;
    sdiv <<= 2;
  }
}

__device__ __forceinline__ void mask_pair(float2* buf, const unsigned char* __restrict__ irb,
                                          int k, float ca, float sa, float cb, float sb) {
  const int m = (4096 - k) & 4095;
  const bool ik = irb[k] != 0;
  const bool im = irb[m] != 0;
  const float2 Zk = buf[k];
  const float2 Zm = buf[m];
  const float Ar = 0.5f * (Zk.x + Zm.x), Ai = 0.5f * (Zk.y - Zm.y);
  const float Br = 0.5f * (Zk.y + Zm.y), Bi = -0.5f * (Zk.x - Zm.x);
  const float Gar = 0.5f * ((ik ? ca : 1.0f) + (im ? ca : 1.0f));
  const float Gai = 0.5f * ((ik ? sa : 0.0f) - (im ? sa : 0.0f));
  const float Gbr = 0.5f * ((ik ? cb : 1.0f) + (im ? cb : 1.0f));
  const float Gbi = 0.5f * ((ik ? sb : 0.0f) - (im ? sb : 0.0f));
  const float har = Gar * Ar - Gai * Ai, hai = Gar * Ai + Gai * Ar;
  const float hbr = Gbr * Br - Gbi * Bi, hbi = Gbr * Bi + Gbi * Br;
  buf[k] = make_float2(har - hbi, hai + hbr);
  buf[m] = make_float2(har + hbi, hbr - hai);
}

__global__ __launch_bounds__(1024) void k_fft4(const float* __restrict__ x,
                                               const unsigned char* __restrict__ irr,
                                               const float* __restrict__ sf,
                                               float* __restrict__ out) {
  __shared__ float2 SA0[4096];
  __shared__ float2 SB0[4096];
  __shared__ float2 SA1[4096];
  __shared__ float2 SB1[4096];
  __shared__ float2 tw[1024];
  const int bb = blockIdx.x >> 6;   // batch
  const int g = blockIdx.x & 63;    // channel group (4 channels)
  const int tid = threadIdx.x;
  {
    float sn, cn;
    sincosf(-1.5339807878856412e-3f * (float)tid, &sn, &cn);  // -2*pi*tid/4096
    tw[tid] = make_float2(cn, sn);
  }
  const float4* xb = reinterpret_cast<const float4*>(x + (size_t)bb * Tc * Dc) + g;
  #pragma unroll
  for (int j = 0; j < 4; ++j) {
    const int t = tid + (j << 10);
    const float4 v = xb[(size_t)t * 64];
    SA0[t] = make_float2(v.x, v.y);
    SA1[t] = make_float2(v.z, v.w);
  }
  __syncthreads();

  fft4_run(SA0, SB0, SA1, SB1, tw, tid, 1.0f);   // forward

  float ca0, sa0, cb0, sb0, ca1, sa1, cb1, sb1;
  sincosf(sf[0], &sa0, &ca0);
  sincosf(sf[1], &sb0, &cb0);
  sincosf(sf[2], &sa1, &ca1);
  sincosf(sf[3], &sb1, &cb1);
  const unsigned char* irb = irr + (size_t)bb * Tc;
  #pragma unroll
  for (int i = 0; i < 2; ++i) {
    const int k = tid + (i << 10);
    mask_pair(SA0, irb, k, ca0, sa0, cb0, sb0);
    mask_pair(SA1, irb, k, ca1, sa1, cb1, sb1);
  }
  if (tid == 0) {
    mask_pair(SA0, irb, 2048, ca0, sa0, cb0, sb0);
    mask_pair(SA1, irb, 2048, ca1, sa1, cb1, sb1);
  }
  __syncthreads();

  fft4_run(SA0, SB0, SA1, SB1, tw, tid, -1.0f);  // inverse (unscaled)

  float4* ob = reinterpret_cast<float4*>(out + (size_t)bb * Tc * Dc) + g;
  constexpr float invN = 1.0f / 4096.0f;
  #pragma unroll
  for (int j = 0; j < 4; ++j) {
    const int t = tid + (j << 10);
    const float2 y0 = SA0[t];
    const float2 y1 = SA1[t];
    ob[(size_t)t * 64] = make_float4(y0.x * invN, y0.y * invN,
                                     y1.x * invN, y1.y * invN);
  }
}

// ---------------- launch ----------------
extern "C" void kernel_launch(void* const* d_in, const int* in_sizes, int n_in,
                              void* d_out, int out_size, void* d_ws, size_t ws_size,
                              hipStream_t stream) {
  const float* x   = (const float*)d_in[0];
  const float* W1  = (const float*)d_in[1];
  const float* b1  = (const float*)d_in[2];
  const float* lng = (const float*)d_in[3];
  const float* lnb = (const float*)d_in[4];
  const float* W2  = (const float*)d_in[5];
  const float* b2  = (const float*)d_in[6];
  const float* tq  = (const float*)d_in[7];
  const float* sf  = (const float*)d_in[8];
  float* out = (float*)d_out;

  // Workspace: unconditional footprint 704768 B (proven safe). Split-weight
  // buffers overlay the scores region (scores dead after k_wsum).
  char* ws = (char*)d_ws;
  float* scores        = (float*)(ws);                    // [0, 524288)
  unsigned short* w1h  = (unsigned short*)(ws);           // overlay [0, 131072)
  unsigned short* w1l  = (unsigned short*)(ws + 131072);  // [131072, 262144)
  unsigned short* w2h  = (unsigned short*)(ws + 262144);  // [262144, 327680)
  unsigned short* w2l  = (unsigned short*)(ws + 327680);  // [327680, 393216)
  float* mt            = (float*)(ws + 524288);           // 32768
  float2* stats        = (float2*)(ws + 557056);          // 256
  float* tnorm         = (float*)(ws + 557312);           // 16384
  unsigned char* irr   = (unsigned char*)(ws + 573696);   // 131072 -> ends 704768

  hipMemsetAsync(mt, 0, Bc * Dc * sizeof(float), stream);

  k_scores<<<Bc * Tc / 32, 256, 0, stream>>>(x, tq, scores);
  k_smstats<<<Bc, 1024, 0, stream>>>(scores, stats);
  k_wsum<<<Bc * 16, 256, 0, stream>>>(x, scores, stats, mt);
  // scores dead from here
  k_prep<<<96, 256, 0, stream>>>(W1, W2, w1h, w1l, w2h, w2l);
  k_tenc<<<Bc, 256, 0, stream>>>(mt, W1, b1, lng, lnb, W2, b2, tnorm);
  k_encode_mfma<<<Bc * Tc / 64, 256, 0, stream>>>(x, w1h, w1l, w2h, w2l,
                                                  b1, lng, lnb, b2, tnorm, irr);
  k_fft4<<<Bc * 64, 1024, 0, stream>>>(x, irr, sf, out);
}